// Round 15
// baseline (335.756 us; speedup 1.0000x reference)
//
#include <hip/hip_runtime.h>
#include <hip/hip_bf16.h>

typedef unsigned short u16;
typedef unsigned int   u32;
typedef float f32x2 __attribute__((ext_vector_type(2)));
typedef float f32x4 __attribute__((ext_vector_type(4)));
typedef short bf16x8 __attribute__((ext_vector_type(8)));

static constexpr int NN = 100000;   // nodes
static constexpr int NE = 1600000;  // edges
static constexpr int NG = 64;       // graphs

static constexpr int BSH   = 8;     // nodes per bucket = 256
static constexpr int NBUCK = 391;   // ceil(NN / 256)
static constexpr int BCAP  = 5120;  // bucket capacity (mean 4096, sd ~64)
static constexpr int PB    = 8;     // pooling partial-blocks per graph

// RTNE f32->bf16
__device__ __forceinline__ u16 bf16rte(float a) {
  u32 u = __builtin_bit_cast(u32, a);
  u = (u + 0x7FFFu + ((u >> 16) & 1u)) >> 16;
  return (u16)u;
}
__device__ __forceinline__ u32 bf16pair(float a, float b) {
  return (u32)bf16rte(a) | ((u32)bf16rte(b) << 16);
}
__device__ __forceinline__ float bflo(u32 u) { return __builtin_bit_cast(float, u << 16); }
__device__ __forceinline__ float bfhi(u32 u) { return __builtin_bit_cast(float, u & 0xFFFF0000u); }

// packed dual-FMA: a.lo += w.lo*bflo(u); a.hi += w.hi*bfhi(u)  (gather loop only)
__device__ __forceinline__ void pkfma(f32x2& a, f32x2 w2, u32 u) {
  f32x2 v;
  v.x = bflo(u); v.y = bfhi(u);
  asm("v_pk_fma_f32 %0, %1, %2, %0" : "+v"(a) : "v"(w2), "v"(v));
}

// W2 LDS slot: pitch 132 f32x2 entries, row XOR-swizzled -> spreads db-lane banks.
__device__ __forceinline__ int w2slot(int pc, int row) {
  return pc * 132 + (row ^ ((row >> 5) & 7));
}

// ---- prep: W1 swizzled (0..63) | gbounds + cur-zero (64) | W2 -> f32 pairs swz (65) ----
__global__ void k_prep(const float* __restrict__ W1, u16* __restrict__ wsTg,
                       const int* __restrict__ batch, int* __restrict__ gstart,
                       int* __restrict__ cur,
                       const float* __restrict__ W2, f32x2* __restrict__ wsW2f) {
  const int bid = blockIdx.x;
  if (bid < 64) {
    int idx = bid * 256 + threadIdx.x;   // 64*256 = 16384 = all of W1
    int k = idx >> 7, c = idx & 127;
    wsTg[c * 128 + (((k >> 3) ^ (c & 7)) << 3) + (k & 7)] = bf16rte(W1[idx]);
  } else if (bid == 64) {
    int t = threadIdx.x;
    for (int i = t; i < NBUCK; i += 256) cur[i] = 0;
    if (t <= NG) {
      int lo = 0, hi = NN;
      while (lo < hi) { int mid = (lo + hi) >> 1; if (batch[mid] < t) lo = mid + 1; else hi = mid; }
      gstart[t] = lo;
    }
  } else {
    const int t = threadIdx.x;
#pragma unroll
    for (int i = 0; i < 10; ++i) {
      int idx = t * 10 + i;            // 2560 entries
      int pc = idx >> 7, d = idx & 127;
      f32x2 v;
      v.x = W2[d * 40 + pc * 2];
      v.y = W2[d * 40 + pc * 2 + 1];
      wsW2f[w2slot(pc, d)] = v;
    }
  }
}

// ---------------- GEMM1 (MFMA bf16): Wh1b = x @ W1, fused es1/ed1 ----------------
__global__ __launch_bounds__(256) void k_gemm1(
    const float* __restrict__ x, const u16* __restrict__ wsTg, const float* __restrict__ a1,
    u16* __restrict__ Wh1b, float* __restrict__ es1, float* __restrict__ ed1)
{
  __shared__ u16 wsT[128][128];   // [col][k], kg' = kg ^ (col&7)  (32 KB)
  __shared__ u16 xsb[64][32];     // [row][k-in-step], kg' = kg ^ ((row>>1)&3)  (4 KB)
  const int t = threadIdx.x;
  const int w = t >> 6, l = t & 63;
  const int rowBase = blockIdx.x * 64;

  {
    const uint4* src = (const uint4*)wsTg;
    uint4* dst = (uint4*)&wsT[0][0];
#pragma unroll
    for (int i = 0; i < 8; ++i) dst[t * 8 + i] = src[t * 8 + i];
  }

  f32x4 acc[4][2];
#pragma unroll
  for (int r = 0; r < 4; ++r)
#pragma unroll
    for (int cf = 0; cf < 2; ++cf) acc[r][cf] = (f32x4){0.f, 0.f, 0.f, 0.f};

  const int rr = t >> 2, cg = t & 3;
  const int grow_s = rowBase + rr;

  for (int kk0 = 0; kk0 < 128; kk0 += 32) {
    float4 v0 = make_float4(0.f, 0.f, 0.f, 0.f), v1 = v0;
    if (grow_s < NN) {
      v0 = *(const float4*)(&x[(size_t)grow_s * 128 + kk0 + cg * 8]);
      v1 = *(const float4*)(&x[(size_t)grow_s * 128 + kk0 + cg * 8 + 4]);
    }
    if (kk0) __syncthreads();
    {
      u32 p0 = bf16pair(v0.x, v0.y);
      u32 p1 = bf16pair(v0.z, v0.w);
      u32 p2 = bf16pair(v1.x, v1.y);
      u32 p3 = bf16pair(v1.z, v1.w);
      int sg = cg ^ ((rr >> 1) & 3);
      *(uint4*)(&xsb[rr][sg * 8]) = make_uint4(p0, p1, p2, p3);
    }
    __syncthreads();

    bf16x8 bfr[2];
#pragma unroll
    for (int cf = 0; cf < 2; ++cf) {
      int col = w * 32 + cf * 16 + (l & 15);
      int kg = (kk0 >> 3) + (l >> 4);
      bfr[cf] = *(const bf16x8*)(&wsT[col][(kg ^ (col & 7)) * 8]);
    }
#pragma unroll
    for (int r = 0; r < 4; ++r) {
      int row = r * 16 + (l & 15);
      int kg = l >> 4;
      bf16x8 afr = *(const bf16x8*)(&xsb[row][(kg ^ ((row >> 1) & 3)) * 8]);
#pragma unroll
      for (int cf = 0; cf < 2; ++cf)
        acc[r][cf] = __builtin_amdgcn_mfma_f32_16x16x32_bf16(afr, bfr[cf], acc[r][cf], 0, 0, 0);
    }
  }

  const int cl = l & 15;
  const int rq = l >> 4;
#pragma unroll
  for (int cf = 0; cf < 2; ++cf) {
    const int h = w * 2 + cf;
    const int gcol = w * 32 + cf * 16 + cl;
    const float as = a1[h * 32 + cl];
    const float ad = a1[h * 32 + 16 + cl];
#pragma unroll
    for (int r = 0; r < 4; ++r) {
#pragma unroll
      for (int i = 0; i < 4; ++i) {
        int grow = rowBase + r * 16 + rq * 4 + i;
        float wh = acc[r][cf][i];
        float ps = wh * as, pd = wh * ad;
        ps += __shfl_xor(ps, 1); ps += __shfl_xor(ps, 2);
        ps += __shfl_xor(ps, 4); ps += __shfl_xor(ps, 8);
        pd += __shfl_xor(pd, 1); pd += __shfl_xor(pd, 2);
        pd += __shfl_xor(pd, 4); pd += __shfl_xor(pd, 8);
        if (grow < NN) {
          Wh1b[(size_t)grow * 128 + gcol] = bf16rte(wh);
          if (cl == 0) { es1[grow * 8 + h] = ps; ed1[grow * 8 + h] = pd; }
        }
      }
    }
  }
}

// ---- Pass B: binning, 2-way replicated counters, DIRECT global scatter ----
__global__ __launch_bounds__(256) void k_bin(
    const int* __restrict__ src, const int* __restrict__ dst,
    int* __restrict__ cur, u32* __restrict__ ebuf)
{
  __shared__ int lcnt2[2][512];
  __shared__ int scn[512];
  __shared__ int goff[NBUCK];
  const int t = threadIdx.x;
  const int wp = (t >> 7) & 1;
  const int e0 = blockIdx.x * 4096;

  lcnt2[0][t] = 0; lcnt2[0][t + 256] = 0;
  lcnt2[1][t] = 0; lcnt2[1][t + 256] = 0;
  __syncthreads();

  u32 ent[16]; short bb[16], lp[16];
#pragma unroll
  for (int i = 0; i < 16; ++i) {
    int e = e0 + i * 256 + t;
    if (e < NE) {
      int s = src[e], d = dst[e];
      int b = d >> BSH;
      ent[i] = (u32)s | ((u32)(d & 255) << 20);
      bb[i] = (short)b;
      lp[i] = (short)atomicAdd(&lcnt2[wp][b], 1);
    } else bb[i] = -1;
  }
  __syncthreads();
  scn[t] = lcnt2[0][t] + lcnt2[1][t];
  scn[t + 256] = lcnt2[0][t + 256] + lcnt2[1][t + 256];
  __syncthreads();
  for (int d = 1; d < 512; d <<= 1) {
    int v0 = (t >= d) ? scn[t - d] : 0;
    int v1 = (t + 256 >= d) ? scn[t + 256 - d] : 0;
    __syncthreads();
    scn[t] += v0; scn[t + 256] += v1;
    __syncthreads();
  }
  for (int b = t; b < NBUCK; b += 256) {
    int excl = b ? scn[b - 1] : 0;
    int cnt = scn[b] - excl;
    if (cnt) goff[b] = b * BCAP + atomicAdd(&cur[b], cnt);
  }
  __syncthreads();
#pragma unroll
  for (int i = 0; i < 16; ++i) {
    if (bb[i] >= 0) {
      int b = bb[i];
      int g = goff[b] + (wp ? lcnt2[0][b] : 0) + lp[i];
      if (g < (b + 1) * BCAP) ebuf[g] = ent[i];
    }
  }
}

// ---------------- Pass C: per-bucket local counting sort ----------------
__global__ __launch_bounds__(256) void k_sort(
    const int* __restrict__ cur, u32* __restrict__ ebuf,
    int* __restrict__ offs, int* __restrict__ deg)
{
  __shared__ u32 ein[BCAP];
  __shared__ u32 eout[BCAP];
  __shared__ int nd[256];
  __shared__ int ncur[256];
  const int t = threadIdx.x;
  const int b = blockIdx.x;
  const int base = b * BCAP;
  int cnt = cur[b];
  if (cnt > BCAP) cnt = BCAP;
  const int nloc = min(256, NN - (b << BSH));

  for (int i = t; i < cnt; i += 256) ein[i] = ebuf[base + i];
  nd[t] = 0;
  __syncthreads();
  for (int i = t; i < cnt; i += 256) atomicAdd(&nd[ein[i] >> 20], 1);
  __syncthreads();
  const int myCnt = nd[t];
  for (int d = 1; d < 256; d <<= 1) {
    int v = (t >= d) ? nd[t - d] : 0;
    __syncthreads();
    nd[t] += v;
    __syncthreads();
  }
  const int excl = t ? nd[t - 1] : 0;
  ncur[t] = excl;
  if (t < nloc) {
    int node = (b << BSH) + t;
    offs[node] = base + excl;
    deg[node]  = myCnt;
  }
  __syncthreads();
  for (int i = t; i < cnt; i += 256) {
    u32 v = ein[i];
    int pos = atomicAdd(&ncur[v >> 20], 1);
    eout[pos] = v & 0xFFFFFu;
  }
  __syncthreads();
  for (int i = t; i < cnt; i += 256) ebuf[base + i] = eout[i];
}

// ---- Layer-1 aggregation FUSED with layer-2 GEMM (scalar epilogue, f32 W2 in LDS) ----
__global__ __launch_bounds__(256) void k_agg1g2(
    const u16* __restrict__ Wh1b, const float* __restrict__ es1, const float* __restrict__ ed1,
    const int* __restrict__ offs, const int* __restrict__ deg, const int* __restrict__ csr,
    const f32x2* __restrict__ wsW2f, const float* __restrict__ a2,
    u16* __restrict__ Wh2b, float* __restrict__ es2, float* __restrict__ ed2)
{
  __shared__ f32x2 W2f[2640];   // [pc 0..19][132], row XOR-swizzled (21.1 KB)
  const int t = threadIdx.x;
  for (int i = t; i < 2640; i += 256) W2f[i] = wsW2f[i];
  __syncthreads();

  const int wid = t >> 6;
  const int lane = t & 63;
  const int n = blockIdx.x * 4 + wid;
  if (n >= NN) return;
  const int s0 = offs[n];
  const int nE = deg[n];
  const int g = lane >> 4;        // edge group 0..3
  const int db = lane & 15;       // dim block
  const int h = db >> 1;          // head
  const float edv = ed1[n * 8 + h];

  f32x2 acc[4];
#pragma unroll
  for (int i = 0; i < 4; ++i) { acc[i].x = 0.f; acc[i].y = 0.f; }
  float ssum = 0.f;

  int c0 = 0;
  for (; c0 + 16 <= nE; c0 += 16) {
    int ss[4];
#pragma unroll
    for (int q = 0; q < 4; ++q) ss[q] = csr[s0 + c0 + q * 4 + g];
    float zz[4];
#pragma unroll
    for (int q = 0; q < 4; ++q) {
      float z = es1[ss[q] * 8 + h] + edv;
      zz[q] = (z > 0.f) ? z : 0.2f * z;
    }
    uint4 raw[4];
#pragma unroll
    for (int q = 0; q < 4; ++q)
      raw[q] = *(const uint4*)(Wh1b + (size_t)ss[q] * 128 + db * 8);
#pragma unroll
    for (int q = 0; q < 4; ++q) {
      const float ww = __expf(zz[q]);
      ssum += ww;
      f32x2 w2; w2.x = ww; w2.y = ww;
      pkfma(acc[0], w2, raw[q].x);
      pkfma(acc[1], w2, raw[q].y);
      pkfma(acc[2], w2, raw[q].z);
      pkfma(acc[3], w2, raw[q].w);
    }
  }
  if (c0 < nE) {
    int jj[4], ss[4];
#pragma unroll
    for (int q = 0; q < 4; ++q) {
      jj[q] = c0 + q * 4 + g;
      ss[q] = csr[s0 + (jj[q] < nE ? jj[q] : 0)];
    }
    float zz[4];
#pragma unroll
    for (int q = 0; q < 4; ++q) {
      float z = es1[ss[q] * 8 + h] + edv;
      zz[q] = (z > 0.f) ? z : 0.2f * z;
    }
#pragma unroll
    for (int q = 0; q < 4; ++q) {
      if (jj[q] < nE) {
        const uint4 raw = *(const uint4*)(Wh1b + (size_t)ss[q] * 128 + db * 8);
        const float ww = __expf(zz[q]);
        ssum += ww;
        f32x2 w2; w2.x = ww; w2.y = ww;
        pkfma(acc[0], w2, raw.x);
        pkfma(acc[1], w2, raw.y);
        pkfma(acc[2], w2, raw.z);
        pkfma(acc[3], w2, raw.w);
      }
    }
  }
  // butterfly: ALL lanes end with the full edge-group sums for their db slice
#pragma unroll
  for (int i = 0; i < 4; ++i) {
    acc[i].x += __shfl_xor(acc[i].x, 16);
    acc[i].y += __shfl_xor(acc[i].y, 16);
    acc[i].x += __shfl_xor(acc[i].x, 32);
    acc[i].y += __shfl_xor(acc[i].y, 32);
  }
  ssum += __shfl_xor(ssum, 16);
  ssum += __shfl_xor(ssum, 32);

  // h1 slice in-register (softmax normalize + ELU), replicated across the 4 groups
  const float inv = 1.f / (ssum + 1e-16f);
  float hv[8];
#pragma unroll
  for (int i = 0; i < 4; ++i) {
    float v0 = acc[i].x * inv;
    float v1 = acc[i].y * inv;
    hv[2 * i]     = (v0 > 0.f) ? v0 : expm1f(v0);
    hv[2 * i + 1] = (v1 > 0.f) ? v1 : expm1f(v1);
  }

  // layer-2 GEMM: group g computes cols g*10..g*10+9; lane covers rows db*8..db*8+7
  float o[10];
#pragma unroll
  for (int j = 0; j < 10; ++j) o[j] = 0.f;
  const int rbase = db * 8;
  const int xr = db >> 2;     // (row>>5)&7 for rows rbase..rbase+7
#pragma unroll
  for (int d = 0; d < 8; ++d) {
    const float hvd = hv[d];
    const int slot = rbase + (d ^ xr);   // swizzled row slot (hv index stays compile-time)
#pragma unroll
    for (int p = 0; p < 5; ++p) {
      const f32x2 wv = W2f[(g * 5 + p) * 132 + slot];
      o[2 * p]     = fmaf(hvd, wv.x, o[2 * p]);
      o[2 * p + 1] = fmaf(hvd, wv.y, o[2 * p + 1]);
    }
  }
  // reduce over the 16 db slices (within group)
#pragma unroll
  for (int j = 0; j < 10; ++j) {
    o[j] += __shfl_xor(o[j], 1);
    o[j] += __shfl_xor(o[j], 2);
    o[j] += __shfl_xor(o[j], 4);
    o[j] += __shfl_xor(o[j], 8);
  }
  if (db == 0) {    // lanes 0,16,32,48: each holds 10 final Wh2 cols
    u32* dst = (u32*)(Wh2b + (size_t)n * 48 + g * 10);
    dst[0] = bf16pair(o[0], o[1]);
    dst[1] = bf16pair(o[2], o[3]);
    dst[2] = bf16pair(o[4], o[5]);
    dst[3] = bf16pair(o[6], o[7]);
    dst[4] = bf16pair(o[8], o[9]);
    float pes = 0.f, ped = 0.f;
#pragma unroll
    for (int j = 0; j < 10; ++j) {
      pes = fmaf(o[j], a2[g * 10 + j], pes);
      ped = fmaf(o[j], a2[40 + g * 10 + j], ped);
    }
    pes += __shfl_xor(pes, 16); pes += __shfl_xor(pes, 32);
    ped += __shfl_xor(ped, 16); ped += __shfl_xor(ped, 32);
    if (lane == 0) { es2[n] = pes; ed2[n] = ped; }
  }
}

// ---------------- Layer-2 aggregation: 6 edge-groups x 10 dim-lanes, h2 out bf16 ----------
__global__ __launch_bounds__(256, 8) void k_agg2(
    const u16* __restrict__ Wh2b, const float* __restrict__ es2, const float* __restrict__ ed2,
    const int* __restrict__ offs, const int* __restrict__ deg, const int* __restrict__ csr,
    u32* __restrict__ h2b)
{
  __shared__ float red[4][64][5];
  const int wid = threadIdx.x >> 6;
  const int lane = threadIdx.x & 63;
  const int n = blockIdx.x * 4 + wid;
  if (n >= NN) return;
  const int s0 = offs[n];
  const int nE = deg[n];
  const float edv = ed2[n];
  int e6 = lane / 10;
  const int r10 = lane - e6 * 10;
  const bool act = lane < 60;
  if (e6 > 5) e6 = 5;

  f32x2 acc0, acc1;
  acc0.x = acc0.y = acc1.x = acc1.y = 0.f;
  float ssum = 0.f;

  for (int c0 = 0; c0 < nE; c0 += 24) {
    int jj[4], ss[4];
#pragma unroll
    for (int q = 0; q < 4; ++q) {
      jj[q] = c0 + q * 6 + e6;
      ss[q] = csr[s0 + (jj[q] < nE ? jj[q] : 0)];
    }
    float zz[4];
#pragma unroll
    for (int q = 0; q < 4; ++q) {
      float z = es2[ss[q]] + edv;
      zz[q] = (z > 0.f) ? z : 0.2f * z;
    }
#pragma unroll
    for (int q = 0; q < 4; ++q) {
      if (act && jj[q] < nE) {
        const uint2 raw = *(const uint2*)(Wh2b + (size_t)ss[q] * 48 + r10 * 4);
        const float ww = __expf(zz[q]);
        ssum += ww;
        f32x2 w2; w2.x = ww; w2.y = ww;
        pkfma(acc0, w2, raw.x);
        pkfma(acc1, w2, raw.y);
      }
    }
  }
  red[wid][lane][0] = acc0.x; red[wid][lane][1] = acc0.y;
  red[wid][lane][2] = acc1.x; red[wid][lane][3] = acc1.y;
  red[wid][lane][4] = ssum;
  __builtin_amdgcn_wave_barrier();
  if (lane < 20) {
    const int rb = lane >> 1;
    const int eA = (lane & 1) * 2;
    float aA = 0.f, aB = 0.f, sm = 0.f;
#pragma unroll
    for (int g = 0; g < 6; ++g) {
      aA += red[wid][g * 10 + rb][eA];
      aB += red[wid][g * 10 + rb][eA + 1];
      sm += red[wid][g * 10][4];
    }
    float inv = 1.f / (sm + 1e-16f);
    h2b[(size_t)n * 20 + lane] = bf16pair(aA * inv, aB * inv);
  }
}

// ---------------- Pooling (h2 in bf16) ----------------
__global__ __launch_bounds__(256) void k_pool1(
    const u32* __restrict__ h2b, const int* __restrict__ gstart,
    float* __restrict__ partial)
{
  __shared__ float lds[25][10][4];
  const int g = blockIdx.x >> 3;
  const int p = blockIdx.x & 7;
  const int t = threadIdx.x;
  const int s0 = gstart[g], s1 = gstart[g + 1];
  const int len = s1 - s0;
  const int chunk = (len + PB - 1) / PB;
  const int start = s0 + p * chunk;
  const int end = min(start + chunk, s1);
  const int slot = t / 10, q = t - slot * 10;
  float4 acc = make_float4(0.f, 0.f, 0.f, 0.f);
  if (slot < 25) {
    for (int n = start + slot; n < end; n += 25) {
      const uint2 v = *(const uint2*)(&h2b[(size_t)n * 20 + q * 2]);
      acc.x += bflo(v.x); acc.y += bfhi(v.x);
      acc.z += bflo(v.y); acc.w += bfhi(v.y);
    }
    lds[slot][q][0] = acc.x; lds[slot][q][1] = acc.y;
    lds[slot][q][2] = acc.z; lds[slot][q][3] = acc.w;
  }
  __syncthreads();
  if (t < 40) {
    const int qq = t >> 2, e = t & 3;
    float s = 0.f;
#pragma unroll
    for (int sl = 0; sl < 25; ++sl) s += lds[sl][qq][e];
    partial[(size_t)blockIdx.x * 40 + t] = s;
  }
}

__global__ void k_pool2(const float* __restrict__ partial, const int* __restrict__ gstart,
                        float* __restrict__ out)
{
  const int g = blockIdx.x;
  const int d = threadIdx.x;
  if (d >= 40) return;
  float s = 0.f;
#pragma unroll
  for (int p = 0; p < PB; ++p) s += partial[(size_t)(g * PB + p) * 40 + d];
  int cnt = gstart[g + 1] - gstart[g];
  if (cnt < 1) cnt = 1;
  out[g * 40 + d] = s / (float)cnt;
}

extern "C" void kernel_launch(void* const* d_in, const int* in_sizes, int n_in,
                              void* d_out, int out_size, void* d_ws, size_t ws_size,
                              hipStream_t stream)
{
  const float* x   = (const float*)d_in[0];
  const float* W1  = (const float*)d_in[1];
  const float* a1  = (const float*)d_in[2];
  const float* W2  = (const float*)d_in[3];
  const float* a2  = (const float*)d_in[4];
  const int* eidx  = (const int*)d_in[5];
  const int* batch = (const int*)d_in[6];
  float* out = (float*)d_out;

  char* ws = (char*)d_ws;
  u16*   Wh1b = (u16*)(ws + 0);              // 25,600,000 B (read by agg1g2)
  u32*   h2b  = (u32*)(ws + 9600000);        //  8,000,000 B (reuse of Wh1b region AFTER agg1g2)
  u16*   Wh2b = (u16*)(ws + 25600000);       //  9,600,000 B (written by agg1g2)
  float* es1  = (float*)(ws + 51200000);     //  3,200,000
  float* ed1  = (float*)(ws + 54400000);     //  3,200,000
  float* es2  = (float*)(ws + 57600000);     //    400,000
  float* ed2  = (float*)(ws + 58000000);     //    400,000
  u32*   ebuf = (u32*)(ws + 58400000);       //  8,007,680 (NBUCK*BCAP*4) -> becomes csr
  int*   offs = (int*)(ws + 66407680);       //    400,000
  int*   deg  = (int*)(ws + 66807680);       //    400,000
  int*   cur  = (int*)(ws + 67207680);       //      2,048
  int*   gstart = (int*)(ws + 67209728);     //        512
  float* partial = (float*)(ws + 67210240);  //     81,920
  u16*   wsTg = (u16*)(ws + 67292160);       //     32,768 (bf16 swizzled W1^T)
  f32x2* wsW2f = (f32x2*)(ws + 67324928);    //     21,120 (f32 W2 col-pairs, swizzled, pitch 132)
  // total ~67.3 MB

  const int* esrc = eidx;
  const int* edst = eidx + NE;

  k_prep<<<66, 256, 0, stream>>>(W1, wsTg, batch, gstart, cur, W2, wsW2f);
  k_gemm1<<<(NN + 63) / 64, 256, 0, stream>>>(x, wsTg, a1, Wh1b, es1, ed1);
  k_bin<<<(NE + 4095) / 4096, 256, 0, stream>>>(esrc, edst, cur, ebuf);
  k_sort<<<NBUCK, 256, 0, stream>>>(cur, ebuf, offs, deg);
  k_agg1g2<<<(NN + 3) / 4, 256, 0, stream>>>(Wh1b, es1, ed1, offs, deg, (const int*)ebuf,
                                             wsW2f, a2, Wh2b, es2, ed2);
  k_agg2<<<(NN + 3) / 4, 256, 0, stream>>>(Wh2b, es2, ed2, offs, deg, (const int*)ebuf, h2b);
  k_pool1<<<NG * PB, 256, 0, stream>>>(h2b, gstart, partial);
  k_pool2<<<NG, 64, 0, stream>>>(partial, gstart, out);
}

// Round 16
// 260.509 us; speedup vs baseline: 1.2888x; 1.2888x over previous
//
#include <hip/hip_runtime.h>
#include <hip/hip_bf16.h>

typedef unsigned short u16;
typedef unsigned int   u32;
typedef float f32x2 __attribute__((ext_vector_type(2)));
typedef float f32x4 __attribute__((ext_vector_type(4)));
typedef short bf16x8 __attribute__((ext_vector_type(8)));

static constexpr int NN = 100000;   // nodes
static constexpr int NE = 1600000;  // edges
static constexpr int NG = 64;       // graphs

static constexpr int BSH   = 8;     // nodes per bucket = 256
static constexpr int NBUCK = 391;   // ceil(NN / 256)
static constexpr int BCAP  = 5120;  // bucket capacity (mean 4096, sd ~64)
static constexpr int PB    = 8;     // pooling partial-blocks per graph

// RTNE f32->bf16
__device__ __forceinline__ u16 bf16rte(float a) {
  u32 u = __builtin_bit_cast(u32, a);
  u = (u + 0x7FFFu + ((u >> 16) & 1u)) >> 16;
  return (u16)u;
}
__device__ __forceinline__ u32 bf16pair(float a, float b) {
  return (u32)bf16rte(a) | ((u32)bf16rte(b) << 16);
}
__device__ __forceinline__ float bflo(u32 u) { return __builtin_bit_cast(float, u << 16); }
__device__ __forceinline__ float bfhi(u32 u) { return __builtin_bit_cast(float, u & 0xFFFF0000u); }

// packed dual-FMA: a.lo += w.lo*bflo(u); a.hi += w.hi*bfhi(u)  (gather loop only)
__device__ __forceinline__ void pkfma(f32x2& a, f32x2 w2, u32 u) {
  f32x2 v;
  v.x = bflo(u); v.y = bfhi(u);
  asm("v_pk_fma_f32 %0, %1, %2, %0" : "+v"(a) : "v"(w2), "v"(v));
}

// ---- prep: W1 swizzled (0..63) | gbounds + cur-zero (64) | W2 -> bf16 pairs (65) ----
// wsW2 layout: [pc 0..19][d 0..127] u32, pc = col-pair (cols 2pc, 2pc+1)
__global__ void k_prep(const float* __restrict__ W1, u16* __restrict__ wsTg,
                       const int* __restrict__ batch, int* __restrict__ gstart,
                       int* __restrict__ cur,
                       const float* __restrict__ W2, u32* __restrict__ wsW2) {
  const int bid = blockIdx.x;
  if (bid < 64) {
    int idx = bid * 256 + threadIdx.x;   // 64*256 = 16384 = all of W1
    int k = idx >> 7, c = idx & 127;
    wsTg[c * 128 + (((k >> 3) ^ (c & 7)) << 3) + (k & 7)] = bf16rte(W1[idx]);
  } else if (bid == 64) {
    int t = threadIdx.x;
    for (int i = t; i < NBUCK; i += 256) cur[i] = 0;
    if (t <= NG) {
      int lo = 0, hi = NN;
      while (lo < hi) { int mid = (lo + hi) >> 1; if (batch[mid] < t) lo = mid + 1; else hi = mid; }
      gstart[t] = lo;
    }
  } else {
    const int t = threadIdx.x;
#pragma unroll
    for (int i = 0; i < 10; ++i) {
      int idx = t * 10 + i;            // 2560 entries
      int pc = idx >> 7, d = idx & 127;
      wsW2[idx] = bf16pair(W2[d * 40 + pc * 2], W2[d * 40 + pc * 2 + 1]);
    }
  }
}

// ---------------- GEMM1 (MFMA bf16): Wh1b = x @ W1, fused es1/ed1 ----------------
__global__ __launch_bounds__(256) void k_gemm1(
    const float* __restrict__ x, const u16* __restrict__ wsTg, const float* __restrict__ a1,
    u16* __restrict__ Wh1b, float* __restrict__ es1, float* __restrict__ ed1)
{
  __shared__ u16 wsT[128][128];   // [col][k], kg' = kg ^ (col&7)  (32 KB)
  __shared__ u16 xsb[64][32];     // [row][k-in-step], kg' = kg ^ ((row>>1)&3)  (4 KB)
  const int t = threadIdx.x;
  const int w = t >> 6, l = t & 63;
  const int rowBase = blockIdx.x * 64;

  {
    const uint4* src = (const uint4*)wsTg;
    uint4* dst = (uint4*)&wsT[0][0];
#pragma unroll
    for (int i = 0; i < 8; ++i) dst[t * 8 + i] = src[t * 8 + i];
  }

  f32x4 acc[4][2];
#pragma unroll
  for (int r = 0; r < 4; ++r)
#pragma unroll
    for (int cf = 0; cf < 2; ++cf) acc[r][cf] = (f32x4){0.f, 0.f, 0.f, 0.f};

  const int rr = t >> 2, cg = t & 3;
  const int grow_s = rowBase + rr;

  for (int kk0 = 0; kk0 < 128; kk0 += 32) {
    float4 v0 = make_float4(0.f, 0.f, 0.f, 0.f), v1 = v0;
    if (grow_s < NN) {
      v0 = *(const float4*)(&x[(size_t)grow_s * 128 + kk0 + cg * 8]);
      v1 = *(const float4*)(&x[(size_t)grow_s * 128 + kk0 + cg * 8 + 4]);
    }
    if (kk0) __syncthreads();
    {
      u32 p0 = bf16pair(v0.x, v0.y);
      u32 p1 = bf16pair(v0.z, v0.w);
      u32 p2 = bf16pair(v1.x, v1.y);
      u32 p3 = bf16pair(v1.z, v1.w);
      int sg = cg ^ ((rr >> 1) & 3);
      *(uint4*)(&xsb[rr][sg * 8]) = make_uint4(p0, p1, p2, p3);
    }
    __syncthreads();

    bf16x8 bfr[2];
#pragma unroll
    for (int cf = 0; cf < 2; ++cf) {
      int col = w * 32 + cf * 16 + (l & 15);
      int kg = (kk0 >> 3) + (l >> 4);
      bfr[cf] = *(const bf16x8*)(&wsT[col][(kg ^ (col & 7)) * 8]);
    }
#pragma unroll
    for (int r = 0; r < 4; ++r) {
      int row = r * 16 + (l & 15);
      int kg = l >> 4;
      bf16x8 afr = *(const bf16x8*)(&xsb[row][(kg ^ ((row >> 1) & 3)) * 8]);
#pragma unroll
      for (int cf = 0; cf < 2; ++cf)
        acc[r][cf] = __builtin_amdgcn_mfma_f32_16x16x32_bf16(afr, bfr[cf], acc[r][cf], 0, 0, 0);
    }
  }

  const int cl = l & 15;
  const int rq = l >> 4;
#pragma unroll
  for (int cf = 0; cf < 2; ++cf) {
    const int h = w * 2 + cf;
    const int gcol = w * 32 + cf * 16 + cl;
    const float as = a1[h * 32 + cl];
    const float ad = a1[h * 32 + 16 + cl];
#pragma unroll
    for (int r = 0; r < 4; ++r) {
#pragma unroll
      for (int i = 0; i < 4; ++i) {
        int grow = rowBase + r * 16 + rq * 4 + i;
        float wh = acc[r][cf][i];
        float ps = wh * as, pd = wh * ad;
        ps += __shfl_xor(ps, 1); ps += __shfl_xor(ps, 2);
        ps += __shfl_xor(ps, 4); ps += __shfl_xor(ps, 8);
        pd += __shfl_xor(pd, 1); pd += __shfl_xor(pd, 2);
        pd += __shfl_xor(pd, 4); pd += __shfl_xor(pd, 8);
        if (grow < NN) {
          Wh1b[(size_t)grow * 128 + gcol] = bf16rte(wh);
          if (cl == 0) { es1[grow * 8 + h] = ps; ed1[grow * 8 + h] = pd; }
        }
      }
    }
  }
}

// ---- Pass B: binning, 2-way replicated counters, DIRECT global scatter ----
__global__ __launch_bounds__(256) void k_bin(
    const int* __restrict__ src, const int* __restrict__ dst,
    int* __restrict__ cur, u32* __restrict__ ebuf)
{
  __shared__ int lcnt2[2][512];
  __shared__ int scn[512];
  __shared__ int goff[NBUCK];
  const int t = threadIdx.x;
  const int wp = (t >> 7) & 1;
  const int e0 = blockIdx.x * 4096;

  lcnt2[0][t] = 0; lcnt2[0][t + 256] = 0;
  lcnt2[1][t] = 0; lcnt2[1][t + 256] = 0;
  __syncthreads();

  u32 ent[16]; short bb[16], lp[16];
#pragma unroll
  for (int i = 0; i < 16; ++i) {
    int e = e0 + i * 256 + t;
    if (e < NE) {
      int s = src[e], d = dst[e];
      int b = d >> BSH;
      ent[i] = (u32)s | ((u32)(d & 255) << 20);
      bb[i] = (short)b;
      lp[i] = (short)atomicAdd(&lcnt2[wp][b], 1);
    } else bb[i] = -1;
  }
  __syncthreads();
  scn[t] = lcnt2[0][t] + lcnt2[1][t];
  scn[t + 256] = lcnt2[0][t + 256] + lcnt2[1][t + 256];
  __syncthreads();
  for (int d = 1; d < 512; d <<= 1) {
    int v0 = (t >= d) ? scn[t - d] : 0;
    int v1 = (t + 256 >= d) ? scn[t + 256 - d] : 0;
    __syncthreads();
    scn[t] += v0; scn[t + 256] += v1;
    __syncthreads();
  }
  for (int b = t; b < NBUCK; b += 256) {
    int excl = b ? scn[b - 1] : 0;
    int cnt = scn[b] - excl;
    if (cnt) goff[b] = b * BCAP + atomicAdd(&cur[b], cnt);
  }
  __syncthreads();
#pragma unroll
  for (int i = 0; i < 16; ++i) {
    if (bb[i] >= 0) {
      int b = bb[i];
      int g = goff[b] + (wp ? lcnt2[0][b] : 0) + lp[i];
      if (g < (b + 1) * BCAP) ebuf[g] = ent[i];
    }
  }
}

// ---------------- Pass C: per-bucket local counting sort ----------------
__global__ __launch_bounds__(256) void k_sort(
    const int* __restrict__ cur, u32* __restrict__ ebuf,
    int* __restrict__ offs, int* __restrict__ deg)
{
  __shared__ u32 ein[BCAP];
  __shared__ u32 eout[BCAP];
  __shared__ int nd[256];
  __shared__ int ncur[256];
  const int t = threadIdx.x;
  const int b = blockIdx.x;
  const int base = b * BCAP;
  int cnt = cur[b];
  if (cnt > BCAP) cnt = BCAP;
  const int nloc = min(256, NN - (b << BSH));

  for (int i = t; i < cnt; i += 256) ein[i] = ebuf[base + i];
  nd[t] = 0;
  __syncthreads();
  for (int i = t; i < cnt; i += 256) atomicAdd(&nd[ein[i] >> 20], 1);
  __syncthreads();
  const int myCnt = nd[t];
  for (int d = 1; d < 256; d <<= 1) {
    int v = (t >= d) ? nd[t - d] : 0;
    __syncthreads();
    nd[t] += v;
    __syncthreads();
  }
  const int excl = t ? nd[t - 1] : 0;
  ncur[t] = excl;
  if (t < nloc) {
    int node = (b << BSH) + t;
    offs[node] = base + excl;
    deg[node]  = myCnt;
  }
  __syncthreads();
  for (int i = t; i < cnt; i += 256) {
    u32 v = ein[i];
    int pos = atomicAdd(&ncur[v >> 20], 1);
    eout[pos] = v & 0xFFFFFu;
  }
  __syncthreads();
  for (int i = t; i < cnt; i += 256) ebuf[base + i] = eout[i];
}

// ---- Layer-1 aggregation FUSED with layer-2 GEMM (R13 epilogue, 8 nodes/block) ----
__global__ __launch_bounds__(512) void k_agg1g2(
    const u16* __restrict__ Wh1b, const float* __restrict__ es1, const float* __restrict__ ed1,
    const int* __restrict__ offs, const int* __restrict__ deg, const int* __restrict__ csr,
    const u32* __restrict__ wsW2, const float* __restrict__ a2,
    u16* __restrict__ Wh2b, float* __restrict__ es2, float* __restrict__ ed2)
{
  __shared__ u32 W2s[2560];   // [pc 0..19][d 0..127] bf16 pairs (10 KB)
  const int t = threadIdx.x;
  for (int i = t; i < 2560; i += 512) W2s[i] = wsW2[i];
  __syncthreads();

  const int wid = t >> 6;
  const int lane = t & 63;
  const int n = blockIdx.x * 8 + wid;
  if (n >= NN) return;
  const int s0 = offs[n];
  const int nE = deg[n];
  const int g = lane >> 4;        // edge group 0..3
  const int db = lane & 15;       // dim block
  const int h = db >> 1;          // head
  const float edv = ed1[n * 8 + h];

  f32x2 acc[4];
#pragma unroll
  for (int i = 0; i < 4; ++i) { acc[i].x = 0.f; acc[i].y = 0.f; }
  float ssum = 0.f;

  int c0 = 0;
  for (; c0 + 16 <= nE; c0 += 16) {
    int ss[4];
#pragma unroll
    for (int q = 0; q < 4; ++q) ss[q] = csr[s0 + c0 + q * 4 + g];
    float zz[4];
#pragma unroll
    for (int q = 0; q < 4; ++q) {
      float z = es1[ss[q] * 8 + h] + edv;
      zz[q] = (z > 0.f) ? z : 0.2f * z;
    }
    uint4 raw[4];
#pragma unroll
    for (int q = 0; q < 4; ++q)
      raw[q] = *(const uint4*)(Wh1b + (size_t)ss[q] * 128 + db * 8);
#pragma unroll
    for (int q = 0; q < 4; ++q) {
      const float ww = __expf(zz[q]);
      ssum += ww;
      f32x2 w2; w2.x = ww; w2.y = ww;
      pkfma(acc[0], w2, raw[q].x);
      pkfma(acc[1], w2, raw[q].y);
      pkfma(acc[2], w2, raw[q].z);
      pkfma(acc[3], w2, raw[q].w);
    }
  }
  if (c0 < nE) {
    int jj[4], ss[4];
#pragma unroll
    for (int q = 0; q < 4; ++q) {
      jj[q] = c0 + q * 4 + g;
      ss[q] = csr[s0 + (jj[q] < nE ? jj[q] : 0)];
    }
    float zz[4];
#pragma unroll
    for (int q = 0; q < 4; ++q) {
      float z = es1[ss[q] * 8 + h] + edv;
      zz[q] = (z > 0.f) ? z : 0.2f * z;
    }
#pragma unroll
    for (int q = 0; q < 4; ++q) {
      if (jj[q] < nE) {
        const uint4 raw = *(const uint4*)(Wh1b + (size_t)ss[q] * 128 + db * 8);
        const float ww = __expf(zz[q]);
        ssum += ww;
        f32x2 w2; w2.x = ww; w2.y = ww;
        pkfma(acc[0], w2, raw.x);
        pkfma(acc[1], w2, raw.y);
        pkfma(acc[2], w2, raw.z);
        pkfma(acc[3], w2, raw.w);
      }
    }
  }
  // butterfly: ALL lanes end with the full edge-group sums for their db slice
#pragma unroll
  for (int i = 0; i < 4; ++i) {
    acc[i].x += __shfl_xor(acc[i].x, 16);
    acc[i].y += __shfl_xor(acc[i].y, 16);
    acc[i].x += __shfl_xor(acc[i].x, 32);
    acc[i].y += __shfl_xor(acc[i].y, 32);
  }
  ssum += __shfl_xor(ssum, 16);
  ssum += __shfl_xor(ssum, 32);

  // h1 slice in-register (softmax normalize + ELU), replicated across the 4 groups
  const float inv = 1.f / (ssum + 1e-16f);
  float hv[8];
#pragma unroll
  for (int i = 0; i < 4; ++i) {
    float v0 = acc[i].x * inv;
    float v1 = acc[i].y * inv;
    hv[2 * i]     = (v0 > 0.f) ? v0 : expm1f(v0);
    hv[2 * i + 1] = (v1 > 0.f) ? v1 : expm1f(v1);
  }

  // layer-2 GEMM: group g computes cols g*10..g*10+9; lane covers d = db*8..db*8+7
  float o[10];
#pragma unroll
  for (int j = 0; j < 10; ++j) o[j] = 0.f;
#pragma unroll
  for (int d = 0; d < 8; ++d) {
    const float hvd = hv[d];
    const int row = db * 8 + d;
#pragma unroll
    for (int p = 0; p < 5; ++p) {
      u32 pr = W2s[(g * 5 + p) * 128 + row];
      o[2 * p]     = fmaf(hvd, bflo(pr), o[2 * p]);
      o[2 * p + 1] = fmaf(hvd, bfhi(pr), o[2 * p + 1]);
    }
  }
  // reduce over the 16 db slices (within group)
#pragma unroll
  for (int j = 0; j < 10; ++j) {
    o[j] += __shfl_xor(o[j], 1);
    o[j] += __shfl_xor(o[j], 2);
    o[j] += __shfl_xor(o[j], 4);
    o[j] += __shfl_xor(o[j], 8);
  }
  if (db == 0) {    // lanes 0,16,32,48: each holds 10 final Wh2 cols
    u32* dst = (u32*)(Wh2b + (size_t)n * 48 + g * 10);
    dst[0] = bf16pair(o[0], o[1]);
    dst[1] = bf16pair(o[2], o[3]);
    dst[2] = bf16pair(o[4], o[5]);
    dst[3] = bf16pair(o[6], o[7]);
    dst[4] = bf16pair(o[8], o[9]);
    float pes = 0.f, ped = 0.f;
#pragma unroll
    for (int j = 0; j < 10; ++j) {
      pes = fmaf(o[j], a2[g * 10 + j], pes);
      ped = fmaf(o[j], a2[40 + g * 10 + j], ped);
    }
    pes += __shfl_xor(pes, 16); pes += __shfl_xor(pes, 32);
    ped += __shfl_xor(ped, 16); ped += __shfl_xor(ped, 32);
    if (lane == 0) { es2[n] = pes; ed2[n] = ped; }
  }
}

// ---------------- Layer-2 aggregation: 6 edge-groups x 10 dim-lanes, h2 out bf16 ----------
__global__ __launch_bounds__(256, 8) void k_agg2(
    const u16* __restrict__ Wh2b, const float* __restrict__ es2, const float* __restrict__ ed2,
    const int* __restrict__ offs, const int* __restrict__ deg, const int* __restrict__ csr,
    u32* __restrict__ h2b)
{
  __shared__ float red[4][64][5];
  const int wid = threadIdx.x >> 6;
  const int lane = threadIdx.x & 63;
  const int n = blockIdx.x * 4 + wid;
  if (n >= NN) return;
  const int s0 = offs[n];
  const int nE = deg[n];
  const float edv = ed2[n];
  int e6 = lane / 10;
  const int r10 = lane - e6 * 10;
  const bool act = lane < 60;
  if (e6 > 5) e6 = 5;

  f32x2 acc0, acc1;
  acc0.x = acc0.y = acc1.x = acc1.y = 0.f;
  float ssum = 0.f;

  for (int c0 = 0; c0 < nE; c0 += 24) {
    int jj[4], ss[4];
#pragma unroll
    for (int q = 0; q < 4; ++q) {
      jj[q] = c0 + q * 6 + e6;
      ss[q] = csr[s0 + (jj[q] < nE ? jj[q] : 0)];
    }
    float zz[4];
#pragma unroll
    for (int q = 0; q < 4; ++q) {
      float z = es2[ss[q]] + edv;
      zz[q] = (z > 0.f) ? z : 0.2f * z;
    }
#pragma unroll
    for (int q = 0; q < 4; ++q) {
      if (act && jj[q] < nE) {
        const uint2 raw = *(const uint2*)(Wh2b + (size_t)ss[q] * 48 + r10 * 4);
        const float ww = __expf(zz[q]);
        ssum += ww;
        f32x2 w2; w2.x = ww; w2.y = ww;
        pkfma(acc0, w2, raw.x);
        pkfma(acc1, w2, raw.y);
      }
    }
  }
  red[wid][lane][0] = acc0.x; red[wid][lane][1] = acc0.y;
  red[wid][lane][2] = acc1.x; red[wid][lane][3] = acc1.y;
  red[wid][lane][4] = ssum;
  __builtin_amdgcn_wave_barrier();
  if (lane < 20) {
    const int rb = lane >> 1;
    const int eA = (lane & 1) * 2;
    float aA = 0.f, aB = 0.f, sm = 0.f;
#pragma unroll
    for (int g = 0; g < 6; ++g) {
      aA += red[wid][g * 10 + rb][eA];
      aB += red[wid][g * 10 + rb][eA + 1];
      sm += red[wid][g * 10][4];
    }
    float inv = 1.f / (sm + 1e-16f);
    h2b[(size_t)n * 20 + lane] = bf16pair(aA * inv, aB * inv);
  }
}

// ---------------- Pooling (h2 in bf16) ----------------
__global__ __launch_bounds__(256) void k_pool1(
    const u32* __restrict__ h2b, const int* __restrict__ gstart,
    float* __restrict__ partial)
{
  __shared__ float lds[25][10][4];
  const int g = blockIdx.x >> 3;
  const int p = blockIdx.x & 7;
  const int t = threadIdx.x;
  const int s0 = gstart[g], s1 = gstart[g + 1];
  const int len = s1 - s0;
  const int chunk = (len + PB - 1) / PB;
  const int start = s0 + p * chunk;
  const int end = min(start + chunk, s1);
  const int slot = t / 10, q = t - slot * 10;
  float4 acc = make_float4(0.f, 0.f, 0.f, 0.f);
  if (slot < 25) {
    for (int n = start + slot; n < end; n += 25) {
      const uint2 v = *(const uint2*)(&h2b[(size_t)n * 20 + q * 2]);
      acc.x += bflo(v.x); acc.y += bfhi(v.x);
      acc.z += bflo(v.y); acc.w += bfhi(v.y);
    }
    lds[slot][q][0] = acc.x; lds[slot][q][1] = acc.y;
    lds[slot][q][2] = acc.z; lds[slot][q][3] = acc.w;
  }
  __syncthreads();
  if (t < 40) {
    const int qq = t >> 2, e = t & 3;
    float s = 0.f;
#pragma unroll
    for (int sl = 0; sl < 25; ++sl) s += lds[sl][qq][e];
    partial[(size_t)blockIdx.x * 40 + t] = s;
  }
}

__global__ void k_pool2(const float* __restrict__ partial, const int* __restrict__ gstart,
                        float* __restrict__ out)
{
  const int g = blockIdx.x;
  const int d = threadIdx.x;
  if (d >= 40) return;
  float s = 0.f;
#pragma unroll
  for (int p = 0; p < PB; ++p) s += partial[(size_t)(g * PB + p) * 40 + d];
  int cnt = gstart[g + 1] - gstart[g];
  if (cnt < 1) cnt = 1;
  out[g * 40 + d] = s / (float)cnt;
}

extern "C" void kernel_launch(void* const* d_in, const int* in_sizes, int n_in,
                              void* d_out, int out_size, void* d_ws, size_t ws_size,
                              hipStream_t stream)
{
  const float* x   = (const float*)d_in[0];
  const float* W1  = (const float*)d_in[1];
  const float* a1  = (const float*)d_in[2];
  const float* W2  = (const float*)d_in[3];
  const float* a2  = (const float*)d_in[4];
  const int* eidx  = (const int*)d_in[5];
  const int* batch = (const int*)d_in[6];
  float* out = (float*)d_out;

  char* ws = (char*)d_ws;
  u16*   Wh1b = (u16*)(ws + 0);              // 25,600,000 B (read by agg1g2)
  u32*   h2b  = (u32*)(ws + 9600000);        //  8,000,000 B (reuse of Wh1b region AFTER agg1g2)
  u16*   Wh2b = (u16*)(ws + 25600000);       //  9,600,000 B (written by agg1g2)
  float* es1  = (float*)(ws + 51200000);     //  3,200,000
  float* ed1  = (float*)(ws + 54400000);     //  3,200,000
  float* es2  = (float*)(ws + 57600000);     //    400,000
  float* ed2  = (float*)(ws + 58000000);     //    400,000
  u32*   ebuf = (u32*)(ws + 58400000);       //  8,007,680 (NBUCK*BCAP*4) -> becomes csr
  int*   offs = (int*)(ws + 66407680);       //    400,000
  int*   deg  = (int*)(ws + 66807680);       //    400,000
  int*   cur  = (int*)(ws + 67207680);       //      2,048
  int*   gstart = (int*)(ws + 67209728);     //        512
  float* partial = (float*)(ws + 67210240);  //     81,920
  u16*   wsTg = (u16*)(ws + 67292160);       //     32,768 (bf16 swizzled W1^T)
  u32*   wsW2 = (u32*)(ws + 67324928);       //     10,240 (bf16 W2 col-pairs)
  // total ~67.3 MB

  const int* esrc = eidx;
  const int* edst = eidx + NE;

  k_prep<<<66, 256, 0, stream>>>(W1, wsTg, batch, gstart, cur, W2, wsW2);
  k_gemm1<<<(NN + 63) / 64, 256, 0, stream>>>(x, wsTg, a1, Wh1b, es1, ed1);
  k_bin<<<(NE + 4095) / 4096, 256, 0, stream>>>(esrc, edst, cur, ebuf);
  k_sort<<<NBUCK, 256, 0, stream>>>(cur, ebuf, offs, deg);
  k_agg1g2<<<(NN + 7) / 8, 512, 0, stream>>>(Wh1b, es1, ed1, offs, deg, (const int*)ebuf,
                                             wsW2, a2, Wh2b, es2, ed2);
  k_agg2<<<(NN + 3) / 4, 256, 0, stream>>>(Wh2b, es2, ed2, offs, deg, (const int*)ebuf, h2b);
  k_pool1<<<NG * PB, 256, 0, stream>>>(h2b, gstart, partial);
  k_pool2<<<NG, 64, 0, stream>>>(partial, gstart, out);
}

// Round 17
// 238.607 us; speedup vs baseline: 1.4072x; 1.0918x over previous
//
#include <hip/hip_runtime.h>
#include <hip/hip_bf16.h>

typedef unsigned short u16;
typedef unsigned int   u32;
typedef float f32x2 __attribute__((ext_vector_type(2)));
typedef float f32x4 __attribute__((ext_vector_type(4)));
typedef short bf16x8 __attribute__((ext_vector_type(8)));

static constexpr int NN = 100000;   // nodes
static constexpr int NE = 1600000;  // edges
static constexpr int NG = 64;       // graphs

static constexpr int BSH   = 8;     // nodes per bucket = 256
static constexpr int NBUCK = 391;   // ceil(NN / 256)
static constexpr int BCAP  = 5120;  // bucket capacity (mean 4096, sd ~64)
static constexpr int PB    = 8;     // pooling partial-blocks per graph

// RTNE f32->bf16
__device__ __forceinline__ u16 bf16rte(float a) {
  u32 u = __builtin_bit_cast(u32, a);
  u = (u + 0x7FFFu + ((u >> 16) & 1u)) >> 16;
  return (u16)u;
}
__device__ __forceinline__ u32 bf16pair(float a, float b) {
  return (u32)bf16rte(a) | ((u32)bf16rte(b) << 16);
}
__device__ __forceinline__ float bflo(u32 u) { return __builtin_bit_cast(float, u << 16); }
__device__ __forceinline__ float bfhi(u32 u) { return __builtin_bit_cast(float, u & 0xFFFF0000u); }

// packed dual-FMA: a.lo += w.lo*bflo(u); a.hi += w.hi*bfhi(u)
__device__ __forceinline__ void pkfma(f32x2& a, f32x2 w2, u32 u) {
  f32x2 v;
  v.x = bflo(u); v.y = bfhi(u);
  asm("v_pk_fma_f32 %0, %1, %2, %0" : "+v"(a) : "v"(w2), "v"(v));
}

// ---- prep: W1 swizzled (0..63) | gbounds + cur-zero (64) | W2 -> bf16 pairs (65) ----
// wsW2 layout: [pc 0..19][d 0..127] u32, pc = col-pair (cols 2pc, 2pc+1)
__global__ void k_prep(const float* __restrict__ W1, u16* __restrict__ wsTg,
                       const int* __restrict__ batch, int* __restrict__ gstart,
                       int* __restrict__ cur,
                       const float* __restrict__ W2, u32* __restrict__ wsW2) {
  const int bid = blockIdx.x;
  if (bid < 64) {
    int idx = bid * 256 + threadIdx.x;   // 64*256 = 16384 = all of W1
    int k = idx >> 7, c = idx & 127;
    wsTg[c * 128 + (((k >> 3) ^ (c & 7)) << 3) + (k & 7)] = bf16rte(W1[idx]);
  } else if (bid == 64) {
    int t = threadIdx.x;
    for (int i = t; i < NBUCK; i += 256) cur[i] = 0;
    if (t <= NG) {
      int lo = 0, hi = NN;
      while (lo < hi) { int mid = (lo + hi) >> 1; if (batch[mid] < t) lo = mid + 1; else hi = mid; }
      gstart[t] = lo;
    }
  } else {
    const int t = threadIdx.x;
#pragma unroll
    for (int i = 0; i < 10; ++i) {
      int idx = t * 10 + i;            // 2560 entries
      int pc = idx >> 7, d = idx & 127;
      wsW2[idx] = bf16pair(W2[d * 40 + pc * 2], W2[d * 40 + pc * 2 + 1]);
    }
  }
}

// ---------------- GEMM1 (MFMA bf16): Wh1b = x @ W1, fused es1/ed1 ----------------
__global__ __launch_bounds__(256) void k_gemm1(
    const float* __restrict__ x, const u16* __restrict__ wsTg, const float* __restrict__ a1,
    u16* __restrict__ Wh1b, float* __restrict__ es1, float* __restrict__ ed1)
{
  __shared__ u16 wsT[128][128];   // [col][k], kg' = kg ^ (col&7)  (32 KB)
  __shared__ u16 xsb[64][32];     // [row][k-in-step], kg' = kg ^ ((row>>1)&3)  (4 KB)
  const int t = threadIdx.x;
  const int w = t >> 6, l = t & 63;
  const int rowBase = blockIdx.x * 64;

  {
    const uint4* src = (const uint4*)wsTg;
    uint4* dst = (uint4*)&wsT[0][0];
#pragma unroll
    for (int i = 0; i < 8; ++i) dst[t * 8 + i] = src[t * 8 + i];
  }

  f32x4 acc[4][2];
#pragma unroll
  for (int r = 0; r < 4; ++r)
#pragma unroll
    for (int cf = 0; cf < 2; ++cf) acc[r][cf] = (f32x4){0.f, 0.f, 0.f, 0.f};

  const int rr = t >> 2, cg = t & 3;
  const int grow_s = rowBase + rr;

  for (int kk0 = 0; kk0 < 128; kk0 += 32) {
    float4 v0 = make_float4(0.f, 0.f, 0.f, 0.f), v1 = v0;
    if (grow_s < NN) {
      v0 = *(const float4*)(&x[(size_t)grow_s * 128 + kk0 + cg * 8]);
      v1 = *(const float4*)(&x[(size_t)grow_s * 128 + kk0 + cg * 8 + 4]);
    }
    if (kk0) __syncthreads();
    {
      u32 p0 = bf16pair(v0.x, v0.y);
      u32 p1 = bf16pair(v0.z, v0.w);
      u32 p2 = bf16pair(v1.x, v1.y);
      u32 p3 = bf16pair(v1.z, v1.w);
      int sg = cg ^ ((rr >> 1) & 3);
      *(uint4*)(&xsb[rr][sg * 8]) = make_uint4(p0, p1, p2, p3);
    }
    __syncthreads();

    bf16x8 bfr[2];
#pragma unroll
    for (int cf = 0; cf < 2; ++cf) {
      int col = w * 32 + cf * 16 + (l & 15);
      int kg = (kk0 >> 3) + (l >> 4);
      bfr[cf] = *(const bf16x8*)(&wsT[col][(kg ^ (col & 7)) * 8]);
    }
#pragma unroll
    for (int r = 0; r < 4; ++r) {
      int row = r * 16 + (l & 15);
      int kg = l >> 4;
      bf16x8 afr = *(const bf16x8*)(&xsb[row][(kg ^ ((row >> 1) & 3)) * 8]);
#pragma unroll
      for (int cf = 0; cf < 2; ++cf)
        acc[r][cf] = __builtin_amdgcn_mfma_f32_16x16x32_bf16(afr, bfr[cf], acc[r][cf], 0, 0, 0);
    }
  }

  const int cl = l & 15;
  const int rq = l >> 4;
#pragma unroll
  for (int cf = 0; cf < 2; ++cf) {
    const int h = w * 2 + cf;
    const int gcol = w * 32 + cf * 16 + cl;
    const float as = a1[h * 32 + cl];
    const float ad = a1[h * 32 + 16 + cl];
#pragma unroll
    for (int r = 0; r < 4; ++r) {
#pragma unroll
      for (int i = 0; i < 4; ++i) {
        int grow = rowBase + r * 16 + rq * 4 + i;
        float wh = acc[r][cf][i];
        float ps = wh * as, pd = wh * ad;
        ps += __shfl_xor(ps, 1); ps += __shfl_xor(ps, 2);
        ps += __shfl_xor(ps, 4); ps += __shfl_xor(ps, 8);
        pd += __shfl_xor(pd, 1); pd += __shfl_xor(pd, 2);
        pd += __shfl_xor(pd, 4); pd += __shfl_xor(pd, 8);
        if (grow < NN) {
          Wh1b[(size_t)grow * 128 + gcol] = bf16rte(wh);
          if (cl == 0) { es1[grow * 8 + h] = ps; ed1[grow * 8 + h] = pd; }
        }
      }
    }
  }
}

// ---- Pass B: binning, 2-way replicated counters, DIRECT global scatter ----
__global__ __launch_bounds__(256) void k_bin(
    const int* __restrict__ src, const int* __restrict__ dst,
    int* __restrict__ cur, u32* __restrict__ ebuf)
{
  __shared__ int lcnt2[2][512];
  __shared__ int scn[512];
  __shared__ int goff[NBUCK];
  const int t = threadIdx.x;
  const int wp = (t >> 7) & 1;
  const int e0 = blockIdx.x * 4096;

  lcnt2[0][t] = 0; lcnt2[0][t + 256] = 0;
  lcnt2[1][t] = 0; lcnt2[1][t + 256] = 0;
  __syncthreads();

  u32 ent[16]; short bb[16], lp[16];
#pragma unroll
  for (int i = 0; i < 16; ++i) {
    int e = e0 + i * 256 + t;
    if (e < NE) {
      int s = src[e], d = dst[e];
      int b = d >> BSH;
      ent[i] = (u32)s | ((u32)(d & 255) << 20);
      bb[i] = (short)b;
      lp[i] = (short)atomicAdd(&lcnt2[wp][b], 1);
    } else bb[i] = -1;
  }
  __syncthreads();
  scn[t] = lcnt2[0][t] + lcnt2[1][t];
  scn[t + 256] = lcnt2[0][t + 256] + lcnt2[1][t + 256];
  __syncthreads();
  for (int d = 1; d < 512; d <<= 1) {
    int v0 = (t >= d) ? scn[t - d] : 0;
    int v1 = (t + 256 >= d) ? scn[t + 256 - d] : 0;
    __syncthreads();
    scn[t] += v0; scn[t + 256] += v1;
    __syncthreads();
  }
  for (int b = t; b < NBUCK; b += 256) {
    int excl = b ? scn[b - 1] : 0;
    int cnt = scn[b] - excl;
    if (cnt) goff[b] = b * BCAP + atomicAdd(&cur[b], cnt);
  }
  __syncthreads();
#pragma unroll
  for (int i = 0; i < 16; ++i) {
    if (bb[i] >= 0) {
      int b = bb[i];
      int g = goff[b] + (wp ? lcnt2[0][b] : 0) + lp[i];
      if (g < (b + 1) * BCAP) ebuf[g] = ent[i];
    }
  }
}

// ---------------- Pass C: per-bucket local counting sort ----------------
__global__ __launch_bounds__(256) void k_sort(
    const int* __restrict__ cur, u32* __restrict__ ebuf,
    int* __restrict__ offs, int* __restrict__ deg)
{
  __shared__ u32 ein[BCAP];
  __shared__ u32 eout[BCAP];
  __shared__ int nd[256];
  __shared__ int ncur[256];
  const int t = threadIdx.x;
  const int b = blockIdx.x;
  const int base = b * BCAP;
  int cnt = cur[b];
  if (cnt > BCAP) cnt = BCAP;
  const int nloc = min(256, NN - (b << BSH));

  for (int i = t; i < cnt; i += 256) ein[i] = ebuf[base + i];
  nd[t] = 0;
  __syncthreads();
  for (int i = t; i < cnt; i += 256) atomicAdd(&nd[ein[i] >> 20], 1);
  __syncthreads();
  const int myCnt = nd[t];
  for (int d = 1; d < 256; d <<= 1) {
    int v = (t >= d) ? nd[t - d] : 0;
    __syncthreads();
    nd[t] += v;
    __syncthreads();
  }
  const int excl = t ? nd[t - 1] : 0;
  ncur[t] = excl;
  if (t < nloc) {
    int node = (b << BSH) + t;
    offs[node] = base + excl;
    deg[node]  = myCnt;
  }
  __syncthreads();
  for (int i = t; i < cnt; i += 256) {
    u32 v = ein[i];
    int pos = atomicAdd(&ncur[v >> 20], 1);
    eout[pos] = v & 0xFFFFFu;
  }
  __syncthreads();
  for (int i = t; i < cnt; i += 256) ebuf[base + i] = eout[i];
}

// ---- Layer-1 aggregation FUSED with layer-2 GEMM: 4-deep MLP gather + in-register
//      h1 (never materialized) -> Wh2b (bf16, stride 48) + es2/ed2 ----
__global__ __launch_bounds__(256) void k_agg1g2(
    const u16* __restrict__ Wh1b, const float* __restrict__ es1, const float* __restrict__ ed1,
    const int* __restrict__ offs, const int* __restrict__ deg, const int* __restrict__ csr,
    const u32* __restrict__ wsW2, const float* __restrict__ a2,
    u16* __restrict__ Wh2b, float* __restrict__ es2, float* __restrict__ ed2)
{
  __shared__ u32 W2s[2560];   // [pc 0..19][d 0..127] bf16 pairs (10 KB)
  const int t = threadIdx.x;
#pragma unroll
  for (int i = 0; i < 10; ++i) W2s[t * 10 + i] = wsW2[t * 10 + i];
  __syncthreads();

  const int wid = t >> 6;
  const int lane = t & 63;
  const int n = blockIdx.x * 4 + wid;
  if (n >= NN) return;
  const int s0 = offs[n];
  const int nE = deg[n];
  const int g = lane >> 4;        // edge group 0..3
  const int db = lane & 15;       // dim block
  const int h = db >> 1;          // head
  const float edv = ed1[n * 8 + h];

  f32x2 acc[4];
#pragma unroll
  for (int i = 0; i < 4; ++i) { acc[i].x = 0.f; acc[i].y = 0.f; }
  float ssum = 0.f;

  int c0 = 0;
  for (; c0 + 16 <= nE; c0 += 16) {
    int ss[4];
#pragma unroll
    for (int q = 0; q < 4; ++q) ss[q] = csr[s0 + c0 + q * 4 + g];
    float zz[4];
#pragma unroll
    for (int q = 0; q < 4; ++q) {
      float z = es1[ss[q] * 8 + h] + edv;
      zz[q] = (z > 0.f) ? z : 0.2f * z;
    }
    uint4 raw[4];
#pragma unroll
    for (int q = 0; q < 4; ++q)
      raw[q] = *(const uint4*)(Wh1b + (size_t)ss[q] * 128 + db * 8);
#pragma unroll
    for (int q = 0; q < 4; ++q) {
      const float ww = __expf(zz[q]);
      ssum += ww;
      f32x2 w2; w2.x = ww; w2.y = ww;
      pkfma(acc[0], w2, raw[q].x);
      pkfma(acc[1], w2, raw[q].y);
      pkfma(acc[2], w2, raw[q].z);
      pkfma(acc[3], w2, raw[q].w);
    }
  }
  if (c0 < nE) {
    int jj[4], ss[4];
#pragma unroll
    for (int q = 0; q < 4; ++q) {
      jj[q] = c0 + q * 4 + g;
      ss[q] = csr[s0 + (jj[q] < nE ? jj[q] : 0)];
    }
    float zz[4];
#pragma unroll
    for (int q = 0; q < 4; ++q) {
      float z = es1[ss[q] * 8 + h] + edv;
      zz[q] = (z > 0.f) ? z : 0.2f * z;
    }
#pragma unroll
    for (int q = 0; q < 4; ++q) {
      if (jj[q] < nE) {
        const uint4 raw = *(const uint4*)(Wh1b + (size_t)ss[q] * 128 + db * 8);
        const float ww = __expf(zz[q]);
        ssum += ww;
        f32x2 w2; w2.x = ww; w2.y = ww;
        pkfma(acc[0], w2, raw.x);
        pkfma(acc[1], w2, raw.y);
        pkfma(acc[2], w2, raw.z);
        pkfma(acc[3], w2, raw.w);
      }
    }
  }
  // butterfly: ALL lanes end with the full edge-group sums for their db slice
#pragma unroll
  for (int i = 0; i < 4; ++i) {
    acc[i].x += __shfl_xor(acc[i].x, 16);
    acc[i].y += __shfl_xor(acc[i].y, 16);
    acc[i].x += __shfl_xor(acc[i].x, 32);
    acc[i].y += __shfl_xor(acc[i].y, 32);
  }
  ssum += __shfl_xor(ssum, 16);
  ssum += __shfl_xor(ssum, 32);

  // h1 slice in-register (softmax normalize + ELU), replicated across the 4 groups
  const float inv = 1.f / (ssum + 1e-16f);
  float hv[8];
#pragma unroll
  for (int i = 0; i < 4; ++i) {
    float v0 = acc[i].x * inv;
    float v1 = acc[i].y * inv;
    hv[2 * i]     = (v0 > 0.f) ? v0 : expm1f(v0);
    hv[2 * i + 1] = (v1 > 0.f) ? v1 : expm1f(v1);
  }

  // layer-2 GEMM: group g computes cols g*10..g*10+9; lane covers d = db*8..db*8+7
  float o[10];
#pragma unroll
  for (int j = 0; j < 10; ++j) o[j] = 0.f;
#pragma unroll
  for (int d = 0; d < 8; ++d) {
    const float hvd = hv[d];
    const int row = db * 8 + d;
#pragma unroll
    for (int p = 0; p < 5; ++p) {
      u32 pr = W2s[(g * 5 + p) * 128 + row];
      o[2 * p]     = fmaf(hvd, bflo(pr), o[2 * p]);
      o[2 * p + 1] = fmaf(hvd, bfhi(pr), o[2 * p + 1]);
    }
  }
  // reduce over the 16 db slices (within group)
#pragma unroll
  for (int j = 0; j < 10; ++j) {
    o[j] += __shfl_xor(o[j], 1);
    o[j] += __shfl_xor(o[j], 2);
    o[j] += __shfl_xor(o[j], 4);
    o[j] += __shfl_xor(o[j], 8);
  }
  if (db == 0) {    // lanes 0,16,32,48: each holds 10 final Wh2 cols
    u32* dst = (u32*)(Wh2b + (size_t)n * 48 + g * 10);
    dst[0] = bf16pair(o[0], o[1]);
    dst[1] = bf16pair(o[2], o[3]);
    dst[2] = bf16pair(o[4], o[5]);
    dst[3] = bf16pair(o[6], o[7]);
    dst[4] = bf16pair(o[8], o[9]);
    float pes = 0.f, ped = 0.f;
#pragma unroll
    for (int j = 0; j < 10; ++j) {
      pes = fmaf(o[j], a2[g * 10 + j], pes);
      ped = fmaf(o[j], a2[40 + g * 10 + j], ped);
    }
    pes += __shfl_xor(pes, 16); pes += __shfl_xor(pes, 32);
    ped += __shfl_xor(ped, 16); ped += __shfl_xor(ped, 32);
    if (lane == 0) { es2[n] = pes; ed2[n] = ped; }
  }
}

// ---------------- Layer-2 aggregation: 6 edge-groups x 10 dim-lanes, h2 out bf16 ----------
__global__ __launch_bounds__(256, 8) void k_agg2(
    const u16* __restrict__ Wh2b, const float* __restrict__ es2, const float* __restrict__ ed2,
    const int* __restrict__ offs, const int* __restrict__ deg, const int* __restrict__ csr,
    u32* __restrict__ h2b)
{
  __shared__ float red[4][64][5];
  const int wid = threadIdx.x >> 6;
  const int lane = threadIdx.x & 63;
  const int n = blockIdx.x * 4 + wid;
  if (n >= NN) return;
  const int s0 = offs[n];
  const int nE = deg[n];
  const float edv = ed2[n];
  int e6 = lane / 10;
  const int r10 = lane - e6 * 10;
  const bool act = lane < 60;
  if (e6 > 5) e6 = 5;

  f32x2 acc0, acc1;
  acc0.x = acc0.y = acc1.x = acc1.y = 0.f;
  float ssum = 0.f;

  for (int c0 = 0; c0 < nE; c0 += 24) {
    int jj[4], ss[4];
#pragma unroll
    for (int q = 0; q < 4; ++q) {
      jj[q] = c0 + q * 6 + e6;
      ss[q] = csr[s0 + (jj[q] < nE ? jj[q] : 0)];
    }
    float zz[4];
#pragma unroll
    for (int q = 0; q < 4; ++q) {
      float z = es2[ss[q]] + edv;
      zz[q] = (z > 0.f) ? z : 0.2f * z;
    }
#pragma unroll
    for (int q = 0; q < 4; ++q) {
      if (act && jj[q] < nE) {
        const uint2 raw = *(const uint2*)(Wh2b + (size_t)ss[q] * 48 + r10 * 4);
        const float ww = __expf(zz[q]);
        ssum += ww;
        f32x2 w2; w2.x = ww; w2.y = ww;
        pkfma(acc0, w2, raw.x);
        pkfma(acc1, w2, raw.y);
      }
    }
  }
  red[wid][lane][0] = acc0.x; red[wid][lane][1] = acc0.y;
  red[wid][lane][2] = acc1.x; red[wid][lane][3] = acc1.y;
  red[wid][lane][4] = ssum;
  __builtin_amdgcn_wave_barrier();
  if (lane < 20) {
    const int rb = lane >> 1;           // dim quad 0..9
    const int eA = (lane & 1) * 2;      // dims eA, eA+1 within quad
    float aA = 0.f, aB = 0.f, sm = 0.f;
#pragma unroll
    for (int g = 0; g < 6; ++g) {
      aA += red[wid][g * 10 + rb][eA];
      aB += red[wid][g * 10 + rb][eA + 1];
      sm += red[wid][g * 10][4];
    }
    float inv = 1.f / (sm + 1e-16f);
    h2b[(size_t)n * 20 + lane] = bf16pair(aA * inv, aB * inv);
  }
}

// ---------------- Pooling (h2 in bf16) ----------------
__global__ __launch_bounds__(256) void k_pool1(
    const u32* __restrict__ h2b, const int* __restrict__ gstart,
    float* __restrict__ partial)
{
  __shared__ float lds[25][10][4];
  const int g = blockIdx.x >> 3;
  const int p = blockIdx.x & 7;
  const int t = threadIdx.x;
  const int s0 = gstart[g], s1 = gstart[g + 1];
  const int len = s1 - s0;
  const int chunk = (len + PB - 1) / PB;
  const int start = s0 + p * chunk;
  const int end = min(start + chunk, s1);
  const int slot = t / 10, q = t - slot * 10;
  float4 acc = make_float4(0.f, 0.f, 0.f, 0.f);
  if (slot < 25) {
    for (int n = start + slot; n < end; n += 25) {
      const uint2 v = *(const uint2*)(&h2b[(size_t)n * 20 + q * 2]);
      acc.x += bflo(v.x); acc.y += bfhi(v.x);
      acc.z += bflo(v.y); acc.w += bfhi(v.y);
    }
    lds[slot][q][0] = acc.x; lds[slot][q][1] = acc.y;
    lds[slot][q][2] = acc.z; lds[slot][q][3] = acc.w;
  }
  __syncthreads();
  if (t < 40) {
    const int qq = t >> 2, e = t & 3;
    float s = 0.f;
#pragma unroll
    for (int sl = 0; sl < 25; ++sl) s += lds[sl][qq][e];
    partial[(size_t)blockIdx.x * 40 + t] = s;
  }
}

__global__ void k_pool2(const float* __restrict__ partial, const int* __restrict__ gstart,
                        float* __restrict__ out)
{
  const int g = blockIdx.x;
  const int d = threadIdx.x;
  if (d >= 40) return;
  float s = 0.f;
#pragma unroll
  for (int p = 0; p < PB; ++p) s += partial[(size_t)(g * PB + p) * 40 + d];
  int cnt = gstart[g + 1] - gstart[g];
  if (cnt < 1) cnt = 1;
  out[g * 40 + d] = s / (float)cnt;
}

extern "C" void kernel_launch(void* const* d_in, const int* in_sizes, int n_in,
                              void* d_out, int out_size, void* d_ws, size_t ws_size,
                              hipStream_t stream)
{
  const float* x   = (const float*)d_in[0];
  const float* W1  = (const float*)d_in[1];
  const float* a1  = (const float*)d_in[2];
  const float* W2  = (const float*)d_in[3];
  const float* a2  = (const float*)d_in[4];
  const int* eidx  = (const int*)d_in[5];
  const int* batch = (const int*)d_in[6];
  float* out = (float*)d_out;

  char* ws = (char*)d_ws;
  u16*   Wh1b = (u16*)(ws + 0);              // 25,600,000 B (read by agg1g2)
  u32*   h2b  = (u32*)(ws + 9600000);        //  8,000,000 B (reuse of Wh1b region AFTER agg1g2)
  u16*   Wh2b = (u16*)(ws + 25600000);       //  9,600,000 B (written by agg1g2)
  float* es1  = (float*)(ws + 51200000);     //  3,200,000
  float* ed1  = (float*)(ws + 54400000);     //  3,200,000
  float* es2  = (float*)(ws + 57600000);     //    400,000
  float* ed2  = (float*)(ws + 58000000);     //    400,000
  u32*   ebuf = (u32*)(ws + 58400000);       //  8,007,680 (NBUCK*BCAP*4) -> becomes csr
  int*   offs = (int*)(ws + 66407680);       //    400,000
  int*   deg  = (int*)(ws + 66807680);       //    400,000
  int*   cur  = (int*)(ws + 67207680);       //      2,048
  int*   gstart = (int*)(ws + 67209728);     //        512
  float* partial = (float*)(ws + 67210240);  //     81,920
  u16*   wsTg = (u16*)(ws + 67292160);       //     32,768 (bf16 swizzled W1^T)
  u32*   wsW2 = (u32*)(ws + 67324928);       //     10,240 (bf16 W2 col-pairs)
  // total ~67.3 MB

  const int* esrc = eidx;
  const int* edst = eidx + NE;

  k_prep<<<66, 256, 0, stream>>>(W1, wsTg, batch, gstart, cur, W2, wsW2);
  k_gemm1<<<(NN + 63) / 64, 256, 0, stream>>>(x, wsTg, a1, Wh1b, es1, ed1);
  k_bin<<<(NE + 4095) / 4096, 256, 0, stream>>>(esrc, edst, cur, ebuf);
  k_sort<<<NBUCK, 256, 0, stream>>>(cur, ebuf, offs, deg);
  k_agg1g2<<<(NN + 3) / 4, 256, 0, stream>>>(Wh1b, es1, ed1, offs, deg, (const int*)ebuf,
                                             wsW2, a2, Wh2b, es2, ed2);
  k_agg2<<<(NN + 3) / 4, 256, 0, stream>>>(Wh2b, es2, ed2, offs, deg, (const int*)ebuf, h2b);
  k_pool1<<<NG * PB, 256, 0, stream>>>(h2b, gstart, partial);
  k_pool2<<<NG, 64, 0, stream>>>(partial, gstart, out);
}